// Round 4
// baseline (4804.405 us; speedup 1.0000x reference)
//
#include <hip/hip_runtime.h>

#define B_SZ    2
#define LSEQ    2048
#define DMODEL  768
#define DINNER  1536
#define NHEADS  24
#define HD      64
#define CDPH    192
#define CONVDIM 4608
#define DIP     6168
#define MROWS   (B_SZ*LSEQ)   // 4096

__device__ __forceinline__ float siluf(float x) {
    return x / (1.0f + __expf(-x));
}

// C[m,n] = sum_k A[m,k] * B[n,k];  A:[M,K] row-major, B:[N,K] row-major.
__global__ __launch_bounds__(256) void gemm_nt_f32(
    const float* __restrict__ A, const float* __restrict__ B,
    float* __restrict__ C, int M, int N, int K)
{
    __shared__ __attribute__((aligned(16))) float As[16][132];
    __shared__ __attribute__((aligned(16))) float Bs[16][68];
    const int ntn = (N + 63) >> 6;
    const int bm = blockIdx.x / ntn;
    const int bn = blockIdx.x - bm * ntn;
    const int m0 = bm << 7, n0 = bn << 6;
    const int tid = threadIdx.x;
    const int tx = tid & 15, ty = tid >> 4;

    float acc[8][4];
#pragma unroll
    for (int i = 0; i < 8; ++i)
#pragma unroll
        for (int j = 0; j < 4; ++j) acc[i][j] = 0.f;

    const int ar = tid >> 1;
    const int ac = (tid & 1) << 3;
    const int br = tid >> 2;
    const int bc = (tid & 3) << 2;
    const float* Ap = A + (size_t)(m0 + ar) * K + ac;
    const bool bval = (n0 + br) < N;
    const float* Bp = B + (size_t)(n0 + br) * K + bc;

    for (int k0 = 0; k0 < K; k0 += 16) {
        const float4 a0 = *(const float4*)(Ap + k0);
        const float4 a1 = *(const float4*)(Ap + k0 + 4);
        float4 bv = make_float4(0.f, 0.f, 0.f, 0.f);
        if (bval) bv = *(const float4*)(Bp + k0);
        __syncthreads();
        As[ac + 0][ar] = a0.x; As[ac + 1][ar] = a0.y;
        As[ac + 2][ar] = a0.z; As[ac + 3][ar] = a0.w;
        As[ac + 4][ar] = a1.x; As[ac + 5][ar] = a1.y;
        As[ac + 6][ar] = a1.z; As[ac + 7][ar] = a1.w;
        Bs[bc + 0][br] = bv.x; Bs[bc + 1][br] = bv.y;
        Bs[bc + 2][br] = bv.z; Bs[bc + 3][br] = bv.w;
        __syncthreads();
#pragma unroll
        for (int k = 0; k < 16; ++k) {
            const float4 av0 = *(const float4*)&As[k][ty << 3];
            const float4 av1 = *(const float4*)&As[k][(ty << 3) + 4];
            const float4 bvv = *(const float4*)&Bs[k][tx << 2];
            const float aa[8] = {av0.x, av0.y, av0.z, av0.w,
                                 av1.x, av1.y, av1.z, av1.w};
            const float bb[4] = {bvv.x, bvv.y, bvv.z, bvv.w};
#pragma unroll
            for (int i = 0; i < 8; ++i)
#pragma unroll
                for (int j = 0; j < 4; ++j)
                    acc[i][j] = fmaf(aa[i], bb[j], acc[i][j]);
        }
    }
#pragma unroll
    for (int i = 0; i < 8; ++i) {
        const int m = m0 + (ty << 3) + i;
        float* Cr = C + (size_t)m * N + n0 + (tx << 2);
#pragma unroll
        for (int j = 0; j < 4; ++j)
            if (n0 + (tx << 2) + j < N) Cr[j] = acc[i][j];
    }
}

// Single-wave scan, R matrices in LDS (no spill), zero barriers.
// Lane l owns: state row l (64 regs), conv channels {l, 64+l, 128+l},
// and computes x/B/C row-l dots from LDS-resident R rows.
// LDS layout Rls[mat][jb][lane] (float4): read #jb by lane l is a contiguous
// 1KB wave-line -> minimal (structural) LDS cost. y/B/C/rdt: uniform
// broadcast reads. Wave-internal LDS write->read needs no barrier
// (validated by round-2 pass).
__global__ __launch_bounds__(64, 1) void mamba_scan1w(
    const float* __restrict__ zx,      // [4096, DIP]
    const float* __restrict__ conv_w,  // [4608, 4]
    const float* __restrict__ conv_b,  // [4608]
    const float* __restrict__ R_x,     // [24,64,64]
    const float* __restrict__ R_B,
    const float* __restrict__ R_C,
    const float* __restrict__ R_dt,    // [24,64]
    const float* __restrict__ dt_bias, // [24]
    const float* __restrict__ A_log,   // [24]
    const float* __restrict__ Dvec,    // [24,64]
    float* __restrict__ yz)            // [4096, 1536]
{
    const int b = blockIdx.x / NHEADS;
    const int h = blockIdx.x % NHEADS;
    const int l = threadIdx.x;  // 0..63

    __shared__ __attribute__((aligned(16))) float4 Rls[3 * 16 * 64]; // 48KB
    __shared__ __attribute__((aligned(16))) float4 rdt4[16];
    __shared__ __attribute__((aligned(16))) float ybuf[64];
    __shared__ __attribute__((aligned(16))) float bbuf[64];
    __shared__ __attribute__((aligned(16))) float cbuf[64];

    // ---- stage R rows into LDS (once) ----
    {
        const size_t ro = ((size_t)h * 64 + l) * 64;
#pragma unroll
        for (int jb = 0; jb < 16; ++jb)
            Rls[jb * 64 + l] = *(const float4*)(R_x + ro + jb * 4);
#pragma unroll
        for (int jb = 0; jb < 16; ++jb)
            Rls[1024 + jb * 64 + l] = *(const float4*)(R_B + ro + jb * 4);
#pragma unroll
        for (int jb = 0; jb < 16; ++jb)
            Rls[2048 + jb * 64 + l] = *(const float4*)(R_C + ro + jb * 4);
    }
    if (l < 16) rdt4[l] = *(const float4*)(R_dt + h * 64 + l * 4);
    ybuf[l] = 0.f;

    const float Aval = -__expf(A_log[h]);
    const float bias = dt_bias[h];
    const float dval = Dvec[h * 64 + l];

    // ---- conv params: 3 channels per lane ----
    float wx0, wx1, wx2, wx3, wb0, wb1, wb2, wb3, wc0, wc1, wc2, wc3;
    float cbx, cbB, cbC;
    {
        const float* cw = conv_w + (size_t)h * CDPH * 4;
        const float4 vx = *(const float4*)(cw + (size_t)l * 4);
        const float4 vb = *(const float4*)(cw + (size_t)(64 + l) * 4);
        const float4 vc = *(const float4*)(cw + (size_t)(128 + l) * 4);
        wx0 = vx.x; wx1 = vx.y; wx2 = vx.z; wx3 = vx.w;
        wb0 = vb.x; wb1 = vb.y; wb2 = vb.z; wb3 = vb.w;
        wc0 = vc.x; wc1 = vc.y; wc2 = vc.z; wc3 = vc.w;
        cbx = conv_b[h * CDPH + l];
        cbB = conv_b[h * CDPH + 64 + l];
        cbC = conv_b[h * CDPH + 128 + l];
    }
    float hx0 = 0.f, hx1 = 0.f, hx2 = 0.f;
    float hB0 = 0.f, hB1 = 0.f, hB2 = 0.f;
    float hC0 = 0.f, hC1 = 0.f, hC2 = 0.f;

    const float* xbc = zx + (size_t)b * LSEQ * DIP + DINNER + h * CDPH;
    const float* zb  = zx + (size_t)b * LSEQ * DIP + h * HD;
    const float* dtr = zx + (size_t)b * LSEQ * DIP + DINNER + CONVDIM + h;
    float* yzb = yz + (size_t)b * LSEQ * DINNER + h * HD;

    float st[64];
#pragma unroll
    for (int j = 0; j < 64; ++j) st[j] = 0.f;

    float vx_c = xbc[l], vB_c = xbc[64 + l], vC_c = xbc[128 + l];
    float z_c = zb[l];
    float dtr_c = dtr[0];

    const float4* yb4 = (const float4*)ybuf;
    const float4* bb4 = (const float4*)bbuf;
    const float4* cb4 = (const float4*)cbuf;

    for (int t = 0; t < LSEQ; ++t) {
        // ---- conv (register history, no cross-lane) ----
        const float xcx = fmaf(wx3, vx_c, fmaf(wx2, hx2, fmaf(wx1, hx1, fmaf(wx0, hx0, cbx))));
        const float xcB = fmaf(wb3, vB_c, fmaf(wb2, hB2, fmaf(wb1, hB1, fmaf(wb0, hB0, cbB))));
        const float xcC = fmaf(wc3, vC_c, fmaf(wc2, hC2, fmaf(wc1, hC1, fmaf(wc0, hC0, cbC))));
        hx0 = hx1; hx1 = hx2; hx2 = vx_c;
        hB0 = hB1; hB1 = hB2; hB2 = vB_c;
        hC0 = hC1; hC1 = hC2; hC2 = vC_c;

        // ---- prefetch t+1 (consumed next iter; nothing drains vmcnt) ----
        const size_t roff = (size_t)((t + 1 < LSEQ) ? t + 1 : t) * DIP;
        const float vx_n = xbc[roff + l];
        const float vB_n = xbc[roff + 64 + l];
        const float vC_n = xbc[roff + 128 + l];
        const float z_n  = zb[roff + l];
        const float dtr_n = dtr[roff];

        // ---- dots: row l of R_x/R_B/R_C (LDS wave-lines) + redundant dt ----
        float ax0 = 0.f, ax1 = 0.f, ab0 = 0.f, ab1 = 0.f;
        float ac0 = 0.f, ac1 = 0.f, ad0 = 0.f, ad1 = 0.f;
#pragma unroll
        for (int jb = 0; jb < 16; ++jb) {
            const float4 y4 = yb4[jb];                 // uniform broadcast
            const float4 rx = Rls[jb * 64 + l];
            const float4 rb = Rls[1024 + jb * 64 + l];
            const float4 rc = Rls[2048 + jb * 64 + l];
            const float4 rd = rdt4[jb];                // uniform broadcast
            ax0 = fmaf(rx.x, y4.x, ax0); ax1 = fmaf(rx.y, y4.y, ax1);
            ax0 = fmaf(rx.z, y4.z, ax0); ax1 = fmaf(rx.w, y4.w, ax1);
            ab0 = fmaf(rb.x, y4.x, ab0); ab1 = fmaf(rb.y, y4.y, ab1);
            ab0 = fmaf(rb.z, y4.z, ab0); ab1 = fmaf(rb.w, y4.w, ab1);
            ac0 = fmaf(rc.x, y4.x, ac0); ac1 = fmaf(rc.y, y4.y, ac1);
            ac0 = fmaf(rc.z, y4.z, ac0); ac1 = fmaf(rc.w, y4.w, ac1);
            ad0 = fmaf(rd.x, y4.x, ad0); ad1 = fmaf(rd.y, y4.y, ad1);
            ad0 = fmaf(rd.z, y4.z, ad0); ad1 = fmaf(rd.w, y4.w, ad1);
        }
        const float xv = siluf(xcx + (ax0 + ax1));
        const float Bm = siluf(xcB + (ab0 + ab1));
        const float Cm = siluf(xcC + (ac0 + ac1));
        bbuf[l] = Bm;
        cbuf[l] = Cm;

        // dt scalar (redundant in all lanes; overlaps B/C LDS round-trip)
        const float dv = dtr_c + (ad0 + ad1) + bias;
        const float dtv = (dv > 15.f) ? dv : __logf(1.f + __expf(dv));
        const float dAv = __expf(dtv * Aval);
        const float kx = dtv * xv;
        const float zg = siluf(z_c);

        // ---- state update + output dot (row l) ----
        float ya0 = 0.f, ya1 = 0.f, ya2 = 0.f, ya3 = 0.f;
#pragma unroll
        for (int jb = 0; jb < 16; ++jb) {
            const float4 bm = bb4[jb];                 // uniform broadcast
            const float4 cm = cb4[jb];
            st[4*jb+0] = fmaf(st[4*jb+0], dAv, kx * bm.x);
            ya0 = fmaf(st[4*jb+0], cm.x, ya0);
            st[4*jb+1] = fmaf(st[4*jb+1], dAv, kx * bm.y);
            ya1 = fmaf(st[4*jb+1], cm.y, ya1);
            st[4*jb+2] = fmaf(st[4*jb+2], dAv, kx * bm.z);
            ya2 = fmaf(st[4*jb+2], cm.z, ya2);
            st[4*jb+3] = fmaf(st[4*jb+3], dAv, kx * bm.w);
            ya3 = fmaf(st[4*jb+3], cm.w, ya3);
        }
        const float yv_new = ((ya0 + ya1) + (ya2 + ya3)) + dval * xv;

        ybuf[l] = yv_new;                              // next step's y_prev
        yzb[(size_t)t * DINNER + l] = yv_new * zg;     // gated output

        vx_c = vx_n; vB_c = vB_n; vC_c = vC_n; z_c = z_n; dtr_c = dtr_n;
    }
}

extern "C" void kernel_launch(void* const* d_in, const int* in_sizes, int n_in,
                              void* d_out, int out_size, void* d_ws, size_t ws_size,
                              hipStream_t stream) {
    const float* u       = (const float*)d_in[0];
    const float* W_in    = (const float*)d_in[1];
    const float* conv_w  = (const float*)d_in[2];
    const float* conv_b  = (const float*)d_in[3];
    const float* R_x     = (const float*)d_in[4];
    const float* R_B     = (const float*)d_in[5];
    const float* R_C     = (const float*)d_in[6];
    const float* R_dt    = (const float*)d_in[7];
    const float* dt_bias = (const float*)d_in[8];
    const float* A_log   = (const float*)d_in[9];
    const float* Dv      = (const float*)d_in[10];
    const float* W_out   = (const float*)d_in[11];
    float* out = (float*)d_out;

    float* zx = (float*)d_ws;                      // [4096, 6168]
    float* yz = zx + (size_t)MROWS * DIP;          // [4096, 1536]

    {   // in-projection
        const int M = MROWS, N = DIP, K = DMODEL;
        const int grid = (M / 128) * ((N + 63) / 64);
        gemm_nt_f32<<<grid, 256, 0, stream>>>(u, W_in, zx, M, N, K);
    }
    mamba_scan1w<<<B_SZ * NHEADS, 64, 0, stream>>>(
        zx, conv_w, conv_b, R_x, R_B, R_C, R_dt, dt_bias, A_log, Dv, yz);
    {   // out-projection
        const int M = MROWS, N = DMODEL, K = DINNER;
        const int grid = (M / 128) * ((N + 63) / 64);
        gemm_nt_f32<<<grid, 256, 0, stream>>>(yz, W_out, out, M, N, K);
    }
}

// Round 5
// 2810.976 us; speedup vs baseline: 1.7092x; 1.7092x over previous
//
#include <hip/hip_runtime.h>

#define B_SZ    2
#define LSEQ    2048
#define DMODEL  768
#define DINNER  1536
#define NHEADS  24
#define HD      64
#define CDPH    192
#define CONVDIM 4608
#define DIP     6168
#define MROWS   (B_SZ*LSEQ)   // 4096

typedef float f2 __attribute__((ext_vector_type(2)));

__device__ __forceinline__ float siluf(float x) {
    return x / (1.0f + __expf(-x));
}

// lgkm-only barrier: global prefetches stay in flight across it.
#define WBAR() do { asm volatile("s_waitcnt lgkmcnt(0)" ::: "memory"); \
                    __builtin_amdgcn_s_barrier();                      \
                    asm volatile("" ::: "memory"); } while (0)

// C[m,n] = sum_k A[m,k] * B[n,k];  A:[M,K] row-major, B:[N,K] row-major.
__global__ __launch_bounds__(256) void gemm_nt_f32(
    const float* __restrict__ A, const float* __restrict__ B,
    float* __restrict__ C, int M, int N, int K)
{
    __shared__ __attribute__((aligned(16))) float As[16][132];
    __shared__ __attribute__((aligned(16))) float Bs[16][68];
    const int ntn = (N + 63) >> 6;
    const int bm = blockIdx.x / ntn;
    const int bn = blockIdx.x - bm * ntn;
    const int m0 = bm << 7, n0 = bn << 6;
    const int tid = threadIdx.x;
    const int tx = tid & 15, ty = tid >> 4;

    float acc[8][4];
#pragma unroll
    for (int i = 0; i < 8; ++i)
#pragma unroll
        for (int j = 0; j < 4; ++j) acc[i][j] = 0.f;

    const int ar = tid >> 1;
    const int ac = (tid & 1) << 3;
    const int br = tid >> 2;
    const int bc = (tid & 3) << 2;
    const float* Ap = A + (size_t)(m0 + ar) * K + ac;
    const bool bval = (n0 + br) < N;
    const float* Bp = B + (size_t)(n0 + br) * K + bc;

    for (int k0 = 0; k0 < K; k0 += 16) {
        const float4 a0 = *(const float4*)(Ap + k0);
        const float4 a1 = *(const float4*)(Ap + k0 + 4);
        float4 bv = make_float4(0.f, 0.f, 0.f, 0.f);
        if (bval) bv = *(const float4*)(Bp + k0);
        __syncthreads();
        As[ac + 0][ar] = a0.x; As[ac + 1][ar] = a0.y;
        As[ac + 2][ar] = a0.z; As[ac + 3][ar] = a0.w;
        As[ac + 4][ar] = a1.x; As[ac + 5][ar] = a1.y;
        As[ac + 6][ar] = a1.z; As[ac + 7][ar] = a1.w;
        Bs[bc + 0][br] = bv.x; Bs[bc + 1][br] = bv.y;
        Bs[bc + 2][br] = bv.z; Bs[bc + 3][br] = bv.w;
        __syncthreads();
#pragma unroll
        for (int k = 0; k < 16; ++k) {
            const float4 av0 = *(const float4*)&As[k][ty << 3];
            const float4 av1 = *(const float4*)&As[k][(ty << 3) + 4];
            const float4 bvv = *(const float4*)&Bs[k][tx << 2];
            const float aa[8] = {av0.x, av0.y, av0.z, av0.w,
                                 av1.x, av1.y, av1.z, av1.w};
            const float bb[4] = {bvv.x, bvv.y, bvv.z, bvv.w};
#pragma unroll
            for (int i = 0; i < 8; ++i)
#pragma unroll
                for (int j = 0; j < 4; ++j)
                    acc[i][j] = fmaf(aa[i], bb[j], acc[i][j]);
        }
    }
#pragma unroll
    for (int i = 0; i < 8; ++i) {
        const int m = m0 + (ty << 3) + i;
        float* Cr = C + (size_t)m * N + n0 + (tx << 2);
#pragma unroll
        for (int j = 0; j < 4; ++j)
            if (n0 + (tx << 2) + j < N) Cr[j] = acc[i][j];
    }
}

// 4-wave scan, 2 lgkm barriers/step, intra-wave shfl_xor reduces, symmetric
// lane work, packed-f32 inner loops.
// Lane (w, g=l>>4, r=l&15): owns row p=16*w+r (x/B/C/dt dots + state rows)
// and state cols n in [16g,16g+16). Conv channels {p,64+p,128+p} held
// redundantly across the 4 g-groups (deterministic).
__global__ __launch_bounds__(256, 1) void mamba_scan4(
    const float* __restrict__ zx,      // [4096, DIP]
    const float* __restrict__ conv_w,  // [4608, 4]
    const float* __restrict__ conv_b,  // [4608]
    const float* __restrict__ R_x,     // [24,64,64]
    const float* __restrict__ R_B,
    const float* __restrict__ R_C,
    const float* __restrict__ R_dt,    // [24,64]
    const float* __restrict__ dt_bias, // [24]
    const float* __restrict__ A_log,   // [24]
    const float* __restrict__ Dvec,    // [24,64]
    float* __restrict__ yz)            // [4096, 1536]
{
    const int b = blockIdx.x / NHEADS;
    const int h = blockIdx.x % NHEADS;
    const int tid = threadIdx.x;
    const int w = tid >> 6;
    const int l = tid & 63;
    const int g = l >> 4;
    const int r = l & 15;
    const int p = (w << 4) + r;   // owned output row 0..63

    __shared__ __attribute__((aligned(16))) float ybuf[64];
    __shared__ __attribute__((aligned(16))) float Bml[64];
    __shared__ __attribute__((aligned(16))) float Cml[64];

    // ---- R row-segments (row p, K-slice [16g,16g+16)) in registers ----
    f2 Rx2[8], Rb2[8], Rc2[8], Rd2[8];
    {
        const size_t ro = ((size_t)h * 64 + p) * 64 + (g << 4);
#pragma unroll
        for (int q = 0; q < 4; ++q) {
            const float4 v = *(const float4*)(R_x + ro + q * 4);
            Rx2[q*2] = f2{v.x, v.y}; Rx2[q*2+1] = f2{v.z, v.w};
        }
#pragma unroll
        for (int q = 0; q < 4; ++q) {
            const float4 v = *(const float4*)(R_B + ro + q * 4);
            Rb2[q*2] = f2{v.x, v.y}; Rb2[q*2+1] = f2{v.z, v.w};
        }
#pragma unroll
        for (int q = 0; q < 4; ++q) {
            const float4 v = *(const float4*)(R_C + ro + q * 4);
            Rc2[q*2] = f2{v.x, v.y}; Rc2[q*2+1] = f2{v.z, v.w};
        }
#pragma unroll
        for (int q = 0; q < 4; ++q) {
            const float4 v = *(const float4*)(R_dt + h * 64 + (g << 4) + q * 4);
            Rd2[q*2] = f2{v.x, v.y}; Rd2[q*2+1] = f2{v.z, v.w};
        }
    }
    const float Aval = -__expf(A_log[h]);
    const float bias = dt_bias[h];
    const float Dp   = Dvec[h * 64 + p];

    // ---- conv params for channels p, 64+p, 128+p ----
    float wx0, wx1, wx2, wx3, wb0, wb1, wb2, wb3, wc0, wc1, wc2, wc3;
    float cbx, cbB, cbC;
    {
        const float* cw = conv_w + (size_t)h * CDPH * 4;
        const float4 vx = *(const float4*)(cw + (size_t)p * 4);
        const float4 vb = *(const float4*)(cw + (size_t)(64 + p) * 4);
        const float4 vc = *(const float4*)(cw + (size_t)(128 + p) * 4);
        wx0 = vx.x; wx1 = vx.y; wx2 = vx.z; wx3 = vx.w;
        wb0 = vb.x; wb1 = vb.y; wb2 = vb.z; wb3 = vb.w;
        wc0 = vc.x; wc1 = vc.y; wc2 = vc.z; wc3 = vc.w;
        cbx = conv_b[h * CDPH + p];
        cbB = conv_b[h * CDPH + 64 + p];
        cbC = conv_b[h * CDPH + 128 + p];
    }
    float hx0 = 0.f, hx1 = 0.f, hx2 = 0.f;
    float hB0 = 0.f, hB1 = 0.f, hB2 = 0.f;
    float hC0 = 0.f, hC1 = 0.f, hC2 = 0.f;

    const float* xbc = zx + (size_t)b * LSEQ * DIP + DINNER + h * CDPH;
    const float* zb  = zx + (size_t)b * LSEQ * DIP + h * HD;
    const float* dtp = zx + (size_t)b * LSEQ * DIP + DINNER + CONVDIM + h;
    float* yzb = yz + (size_t)b * LSEQ * DINNER + h * HD;

    f2 st2[8];
#pragma unroll
    for (int q = 0; q < 8; ++q) st2[q] = f2{0.f, 0.f};

    if (g == 0) ybuf[p] = 0.f;
    __syncthreads();

    float vx_c = xbc[p], vB_c = xbc[64 + p], vC_c = xbc[128 + p];
    float z_c = zb[p];
    float dtr_c = dtp[0];

    for (int t = 0; t < LSEQ; ++t) {
        // ---- conv (register history, g-redundant) ----
        const float xcx = fmaf(wx3, vx_c, fmaf(wx2, hx2, fmaf(wx1, hx1, fmaf(wx0, hx0, cbx))));
        const float xcB = fmaf(wb3, vB_c, fmaf(wb2, hB2, fmaf(wb1, hB1, fmaf(wb0, hB0, cbB))));
        const float xcC = fmaf(wc3, vC_c, fmaf(wc2, hC2, fmaf(wc1, hC1, fmaf(wc0, hC0, cbC))));
        hx0 = hx1; hx1 = hx2; hx2 = vx_c;
        hB0 = hB1; hB1 = hB2; hB2 = vB_c;
        hC0 = hC1; hC1 = hC2; hC2 = vC_c;

        // ---- prefetch t+1 (never drained: lgkm-only barriers) ----
        const size_t roff = (size_t)((t + 1 < LSEQ) ? t + 1 : t) * DIP;
        const float vx_n = xbc[roff + p];
        const float vB_n = xbc[roff + 64 + p];
        const float vC_n = xbc[roff + 128 + p];
        const float z_n  = zb[roff + p];
        const float dtr_n = dtp[roff];

        // ---- phase A: 16-K partial dots for row p ----
        const f2* yb2 = (const f2*)(ybuf + (g << 4));
        f2 ax2 = {0.f, 0.f}, ab2 = {0.f, 0.f}, ac2 = {0.f, 0.f}, ad2 = {0.f, 0.f};
#pragma unroll
        for (int q = 0; q < 8; ++q) {
            const f2 y2 = yb2[q];
            ax2 += Rx2[q] * y2;
            ab2 += Rb2[q] * y2;
            ac2 += Rc2[q] * y2;
            ad2 += Rd2[q] * y2;
        }
        float ax = ax2.x + ax2.y, ab = ab2.x + ab2.y;
        float ac = ac2.x + ac2.y, ad = ad2.x + ad2.y;
        // reduce over the 4 g-groups (intra-wave, no barrier)
        ax += __shfl_xor(ax, 16, 64);
        ab += __shfl_xor(ab, 16, 64);
        ac += __shfl_xor(ac, 16, 64);
        ad += __shfl_xor(ad, 16, 64);
        ax += __shfl_xor(ax, 32, 64);
        ab += __shfl_xor(ab, 32, 64);
        ac += __shfl_xor(ac, 32, 64);
        ad += __shfl_xor(ad, 32, 64);

        const float xv = siluf(xcx + ax);
        const float Bm = siluf(xcB + ab);
        const float Cm = siluf(xcC + ac);
        const float dv = dtr_c + ad + bias;
        const float dtv = (dv > 15.f) ? dv : __logf(1.f + __expf(dv));
        const float dAv = __expf(dtv * Aval);
        const float kx = dtv * xv;
        const float zg = siluf(z_c);
        if (g == 0) { Bml[p] = Bm; Cml[p] = Cm; }
        WBAR();  // 1: Bm/Cm visible block-wide

        // ---- phase B: state update + y partial over cols [16g,16g+16) ----
        const f2* bm2 = (const f2*)(Bml + (g << 4));
        const f2* cm2 = (const f2*)(Cml + (g << 4));
        const f2 dA2 = {dAv, dAv};
        const f2 kx2 = {kx, kx};
        f2 yp2 = {0.f, 0.f};
#pragma unroll
        for (int q = 0; q < 8; ++q) {
            st2[q] = st2[q] * dA2 + kx2 * bm2[q];
            yp2 += st2[q] * cm2[q];
        }
        float yp = yp2.x + yp2.y;
        yp += __shfl_xor(yp, 16, 64);
        yp += __shfl_xor(yp, 32, 64);
        const float ynew = yp + Dp * xv;

        if (g == 0) {
            ybuf[p] = ynew;                              // next step's y_prev
            yzb[(size_t)t * DINNER + p] = ynew * zg;     // gated output
        }
        WBAR();  // 2: y visible block-wide

        vx_c = vx_n; vB_c = vB_n; vC_c = vC_n; z_c = z_n; dtr_c = dtr_n;
    }
}

extern "C" void kernel_launch(void* const* d_in, const int* in_sizes, int n_in,
                              void* d_out, int out_size, void* d_ws, size_t ws_size,
                              hipStream_t stream) {
    const float* u       = (const float*)d_in[0];
    const float* W_in    = (const float*)d_in[1];
    const float* conv_w  = (const float*)d_in[2];
    const float* conv_b  = (const float*)d_in[3];
    const float* R_x     = (const float*)d_in[4];
    const float* R_B     = (const float*)d_in[5];
    const float* R_C     = (const float*)d_in[6];
    const float* R_dt    = (const float*)d_in[7];
    const float* dt_bias = (const float*)d_in[8];
    const float* A_log   = (const float*)d_in[9];
    const float* Dv      = (const float*)d_in[10];
    const float* W_out   = (const float*)d_in[11];
    float* out = (float*)d_out;

    float* zx = (float*)d_ws;                      // [4096, 6168]
    float* yz = zx + (size_t)MROWS * DIP;          // [4096, 1536]

    {   // in-projection
        const int M = MROWS, N = DIP, K = DMODEL;
        const int grid = (M / 128) * ((N + 63) / 64);
        gemm_nt_f32<<<grid, 256, 0, stream>>>(u, W_in, zx, M, N, K);
    }
    mamba_scan4<<<B_SZ * NHEADS, 256, 0, stream>>>(
        zx, conv_w, conv_b, R_x, R_B, R_C, R_dt, dt_bias, A_log, Dv, yz);
    {   // out-projection
        const int M = MROWS, N = DMODEL, K = DINNER;
        const int grid = (M / 128) * ((N + 63) / 64);
        gemm_nt_f32<<<grid, 256, 0, stream>>>(yz, W_out, out, M, N, K);
    }
}

// Round 6
// 2569.279 us; speedup vs baseline: 1.8699x; 1.0941x over previous
//
#include <hip/hip_runtime.h>

#define B_SZ    2
#define LSEQ    2048
#define DMODEL  768
#define DINNER  1536
#define NHEADS  24
#define HD      64
#define CDPH    192
#define CONVDIM 4608
#define DIP     6168
#define MROWS   (B_SZ*LSEQ)   // 4096

typedef float f2 __attribute__((ext_vector_type(2)));

__device__ __forceinline__ float siluf(float x) {
    return x / (1.0f + __expf(-x));
}

// lgkm-only barrier: global prefetches stay in flight across it.
#define WBAR() do { asm volatile("s_waitcnt lgkmcnt(0)" ::: "memory"); \
                    __builtin_amdgcn_s_barrier();                      \
                    asm volatile("" ::: "memory"); } while (0)

// Sum over the 4 g-groups (lane, lane^16, lane^32, lane^48), result in all
// lanes. xor16 via ds_swizzle (one LDS op), xor32 via v_permlane32_swap_b32
// (pure VALU: a_new has [lo,lo] halves, b_new has [hi,hi] -> a+b = full sum).
__device__ __forceinline__ float redux4(float v) {
    float o = __int_as_float(
        __builtin_amdgcn_ds_swizzle(__float_as_int(v), 0x401F));  // xor 16
    float s = v + o;
    float a = s, b = s;
    asm("v_permlane32_swap_b32 %0, %1" : "+v"(a), "+v"(b));
    return a + b;
}

// C[m,n] = sum_k A[m,k] * B[n,k];  A:[M,K] row-major, B:[N,K] row-major.
// BM=128, BN=128, BK=16, 256 threads, 8x8 micro-tile, packed-f32 FMA.
__global__ __launch_bounds__(256) void gemm_nt_f32(
    const float* __restrict__ A, const float* __restrict__ B,
    float* __restrict__ C, int M, int N, int K)
{
    __shared__ __attribute__((aligned(16))) float As[16][132];
    __shared__ __attribute__((aligned(16))) float Bs[16][132];
    const int ntn = (N + 127) >> 7;
    const int bm = blockIdx.x / ntn;
    const int bn = blockIdx.x - bm * ntn;
    const int m0 = bm << 7, n0 = bn << 7;
    const int tid = threadIdx.x;
    const int tx = tid & 15, ty = tid >> 4;

    f2 acc[8][4];
#pragma unroll
    for (int i = 0; i < 8; ++i)
#pragma unroll
        for (int j = 0; j < 4; ++j) acc[i][j] = f2{0.f, 0.f};

    const int ar = tid >> 1;          // 0..127
    const int ac = (tid & 1) << 3;    // 0 or 8
    const float* Ap = A + (size_t)(m0 + ar) * K + ac;
    const bool bval = (n0 + ar) < N;
    const float* Bp = B + (size_t)(n0 + ar) * K + ac;

    for (int k0 = 0; k0 < K; k0 += 16) {
        const float4 a0 = *(const float4*)(Ap + k0);
        const float4 a1 = *(const float4*)(Ap + k0 + 4);
        float4 b0 = make_float4(0.f, 0.f, 0.f, 0.f);
        float4 b1 = make_float4(0.f, 0.f, 0.f, 0.f);
        if (bval) {
            b0 = *(const float4*)(Bp + k0);
            b1 = *(const float4*)(Bp + k0 + 4);
        }
        __syncthreads();
        As[ac + 0][ar] = a0.x; As[ac + 1][ar] = a0.y;
        As[ac + 2][ar] = a0.z; As[ac + 3][ar] = a0.w;
        As[ac + 4][ar] = a1.x; As[ac + 5][ar] = a1.y;
        As[ac + 6][ar] = a1.z; As[ac + 7][ar] = a1.w;
        Bs[ac + 0][ar] = b0.x; Bs[ac + 1][ar] = b0.y;
        Bs[ac + 2][ar] = b0.z; Bs[ac + 3][ar] = b0.w;
        Bs[ac + 4][ar] = b1.x; Bs[ac + 5][ar] = b1.y;
        Bs[ac + 6][ar] = b1.z; Bs[ac + 7][ar] = b1.w;
        __syncthreads();
#pragma unroll
        for (int k = 0; k < 16; ++k) {
            const float4 av0 = *(const float4*)&As[k][ty << 3];
            const float4 av1 = *(const float4*)&As[k][(ty << 3) + 4];
            const float4 bv0 = *(const float4*)&Bs[k][tx << 3];
            const float4 bv1 = *(const float4*)&Bs[k][(tx << 3) + 4];
            const float aa[8] = {av0.x, av0.y, av0.z, av0.w,
                                 av1.x, av1.y, av1.z, av1.w};
            f2 bb[4];
            bb[0] = f2{bv0.x, bv0.y}; bb[1] = f2{bv0.z, bv0.w};
            bb[2] = f2{bv1.x, bv1.y}; bb[3] = f2{bv1.z, bv1.w};
#pragma unroll
            for (int i = 0; i < 8; ++i) {
                const f2 a2 = {aa[i], aa[i]};
#pragma unroll
                for (int j = 0; j < 4; ++j)
                    acc[i][j] += a2 * bb[j];
            }
        }
    }
#pragma unroll
    for (int i = 0; i < 8; ++i) {
        const int m = m0 + (ty << 3) + i;
        float* Cr = C + (size_t)m * N + n0 + (tx << 3);
#pragma unroll
        for (int j = 0; j < 4; ++j) {
            const int nc = n0 + (tx << 3) + j * 2;
            if (nc < N)     Cr[j * 2]     = acc[i][j].x;
            if (nc + 1 < N) Cr[j * 2 + 1] = acc[i][j].y;
        }
    }
}

// 4-wave scan, 2 lgkm barriers/step, swizzle+permlane reduces.
// Lane (w, g=l>>4, r=l&15): owns row p=16*w+r and state cols [16g,16g+16).
__global__ __launch_bounds__(256, 1) void mamba_scan5(
    const float* __restrict__ zx,      // [4096, DIP]
    const float* __restrict__ conv_w,  // [4608, 4]
    const float* __restrict__ conv_b,  // [4608]
    const float* __restrict__ R_x,     // [24,64,64]
    const float* __restrict__ R_B,
    const float* __restrict__ R_C,
    const float* __restrict__ R_dt,    // [24,64]
    const float* __restrict__ dt_bias, // [24]
    const float* __restrict__ A_log,   // [24]
    const float* __restrict__ Dvec,    // [24,64]
    float* __restrict__ yz)            // [4096, 1536]
{
    const int b = blockIdx.x / NHEADS;
    const int h = blockIdx.x % NHEADS;
    const int tid = threadIdx.x;
    const int w = tid >> 6;
    const int l = tid & 63;
    const int g = l >> 4;
    const int r = l & 15;
    const int p = (w << 4) + r;   // owned output row 0..63

    __shared__ __attribute__((aligned(16))) float ybuf[64];
    __shared__ __attribute__((aligned(16))) float Bml[64];
    __shared__ __attribute__((aligned(16))) float Cml[64];

    // R row-segments (row p, K-slice [16g,16g+16)) in registers
    f2 Rx2[8], Rb2[8], Rc2[8], Rd2[8];
    {
        const size_t ro = ((size_t)h * 64 + p) * 64 + (g << 4);
#pragma unroll
        for (int q = 0; q < 4; ++q) {
            const float4 v = *(const float4*)(R_x + ro + q * 4);
            Rx2[q*2] = f2{v.x, v.y}; Rx2[q*2+1] = f2{v.z, v.w};
        }
#pragma unroll
        for (int q = 0; q < 4; ++q) {
            const float4 v = *(const float4*)(R_B + ro + q * 4);
            Rb2[q*2] = f2{v.x, v.y}; Rb2[q*2+1] = f2{v.z, v.w};
        }
#pragma unroll
        for (int q = 0; q < 4; ++q) {
            const float4 v = *(const float4*)(R_C + ro + q * 4);
            Rc2[q*2] = f2{v.x, v.y}; Rc2[q*2+1] = f2{v.z, v.w};
        }
#pragma unroll
        for (int q = 0; q < 4; ++q) {
            const float4 v = *(const float4*)(R_dt + h * 64 + (g << 4) + q * 4);
            Rd2[q*2] = f2{v.x, v.y}; Rd2[q*2+1] = f2{v.z, v.w};
        }
    }
    const float Aval = -__expf(A_log[h]);
    const float bias = dt_bias[h];
    const float Dp   = Dvec[h * 64 + p];

    // conv params for channels p, 64+p, 128+p (g-redundant)
    float wx0, wx1, wx2, wx3, wb0, wb1, wb2, wb3, wc0, wc1, wc2, wc3;
    float cbx, cbB, cbC;
    {
        const float* cw = conv_w + (size_t)h * CDPH * 4;
        const float4 vx = *(const float4*)(cw + (size_t)p * 4);
        const float4 vb = *(const float4*)(cw + (size_t)(64 + p) * 4);
        const float4 vc = *(const float4*)(cw + (size_t)(128 + p) * 4);
        wx0 = vx.x; wx1 = vx.y; wx2 = vx.z; wx3 = vx.w;
        wb0 = vb.x; wb1 = vb.y; wb2 = vb.z; wb3 = vb.w;
        wc0 = vc.x; wc1 = vc.y; wc2 = vc.z; wc3 = vc.w;
        cbx = conv_b[h * CDPH + p];
        cbB = conv_b[h * CDPH + 64 + p];
        cbC = conv_b[h * CDPH + 128 + p];
    }
    float hx0 = 0.f, hx1 = 0.f, hx2 = 0.f;
    float hB0 = 0.f, hB1 = 0.f, hB2 = 0.f;
    float hC0 = 0.f, hC1 = 0.f, hC2 = 0.f;

    const float* xbc = zx + (size_t)b * LSEQ * DIP + DINNER + h * CDPH;
    const float* zb  = zx + (size_t)b * LSEQ * DIP + h * HD;
    const float* dtp = zx + (size_t)b * LSEQ * DIP + DINNER + CONVDIM + h;
    float* yzb = yz + (size_t)b * LSEQ * DINNER + h * HD;

    f2 st2[8];
#pragma unroll
    for (int q = 0; q < 8; ++q) st2[q] = f2{0.f, 0.f};

    if (g == 0) ybuf[p] = 0.f;
    __syncthreads();

    float vx_c = xbc[p], vB_c = xbc[64 + p], vC_c = xbc[128 + p];
    float z_c = zb[p];
    float dtr_c = dtp[0];

    for (int t = 0; t < LSEQ; ++t) {
        // ---- conv (register history) ----
        const float xcx = fmaf(wx3, vx_c, fmaf(wx2, hx2, fmaf(wx1, hx1, fmaf(wx0, hx0, cbx))));
        const float xcB = fmaf(wb3, vB_c, fmaf(wb2, hB2, fmaf(wb1, hB1, fmaf(wb0, hB0, cbB))));
        const float xcC = fmaf(wc3, vC_c, fmaf(wc2, hC2, fmaf(wc1, hC1, fmaf(wc0, hC0, cbC))));
        hx0 = hx1; hx1 = hx2; hx2 = vx_c;
        hB0 = hB1; hB1 = hB2; hB2 = vB_c;
        hC0 = hC1; hC1 = hC2; hC2 = vC_c;

        // ---- prefetch t+1 (vmcnt-only; never drained by WBAR) ----
        const size_t roff = (size_t)((t + 1 < LSEQ) ? t + 1 : t) * DIP;
        const float vx_n = xbc[roff + p];
        const float vB_n = xbc[roff + 64 + p];
        const float vC_n = xbc[roff + 128 + p];
        const float z_n  = zb[roff + p];
        const float dtr_n = dtp[roff];

        // ---- phase A: 16-K partial dots for row p ----
        const float4* yb4 = (const float4*)(ybuf + (g << 4));
        f2 ax2 = {0.f, 0.f}, ab2 = {0.f, 0.f}, ac2 = {0.f, 0.f}, ad2 = {0.f, 0.f};
#pragma unroll
        for (int qq = 0; qq < 4; ++qq) {
            const float4 y4 = yb4[qq];
            const f2 ylo = {y4.x, y4.y}, yhi = {y4.z, y4.w};
            ax2 += Rx2[qq*2] * ylo; ax2 += Rx2[qq*2+1] * yhi;
            ab2 += Rb2[qq*2] * ylo; ab2 += Rb2[qq*2+1] * yhi;
            ac2 += Rc2[qq*2] * ylo; ac2 += Rc2[qq*2+1] * yhi;
            ad2 += Rd2[qq*2] * ylo; ad2 += Rd2[qq*2+1] * yhi;
        }
        const float ax = ax2.x + ax2.y, ab = ab2.x + ab2.y;
        const float ac = ac2.x + ac2.y, ad = ad2.x + ad2.y;

        // ---- reduce B,C; publish ----
        const float Bm = siluf(xcB + redux4(ab));
        const float Cm = siluf(xcC + redux4(ac));
        if (g == 0) { Bml[p] = Bm; Cml[p] = Cm; }
        WBAR();  // 1

        // ---- issue B/C window reads; overlap x/dt reduce + dt chain ----
        const float4* bm4 = (const float4*)(Bml + (g << 4));
        const float4* cm4 = (const float4*)(Cml + (g << 4));
        const float4 bA = bm4[0], bB = bm4[1], bC = bm4[2], bD = bm4[3];
        const float4 cA = cm4[0], cB = cm4[1], cC = cm4[2], cD = cm4[3];

        const float xv = siluf(xcx + redux4(ax));
        const float dv = dtr_c + redux4(ad) + bias;
        const float dtv = (dv > 15.f) ? dv : __logf(1.f + __expf(dv));
        const float dAv = __expf(dtv * Aval);
        const float kx = dtv * xv;
        const float zg = siluf(z_c);

        // ---- phase B: state update + y partial over cols [16g,16g+16) ----
        const f2 dA2 = {dAv, dAv};
        const f2 kx2 = {kx, kx};
        f2 bmv[8], cmv[8];
        bmv[0] = f2{bA.x, bA.y}; bmv[1] = f2{bA.z, bA.w};
        bmv[2] = f2{bB.x, bB.y}; bmv[3] = f2{bB.z, bB.w};
        bmv[4] = f2{bC.x, bC.y}; bmv[5] = f2{bC.z, bC.w};
        bmv[6] = f2{bD.x, bD.y}; bmv[7] = f2{bD.z, bD.w};
        cmv[0] = f2{cA.x, cA.y}; cmv[1] = f2{cA.z, cA.w};
        cmv[2] = f2{cB.x, cB.y}; cmv[3] = f2{cB.z, cB.w};
        cmv[4] = f2{cC.x, cC.y}; cmv[5] = f2{cC.z, cC.w};
        cmv[6] = f2{cD.x, cD.y}; cmv[7] = f2{cD.z, cD.w};
        f2 yp2 = {0.f, 0.f};
#pragma unroll
        for (int q = 0; q < 8; ++q) {
            st2[q] = st2[q] * dA2 + kx2 * bmv[q];
            yp2 += st2[q] * cmv[q];
        }
        float yp = yp2.x + yp2.y;
        yp = redux4(yp);
        const float ynew = yp + Dp * xv;

        if (g == 0) {
            ybuf[p] = ynew;                              // next step's y_prev
            yzb[(size_t)t * DINNER + p] = ynew * zg;     // gated output
        }
        WBAR();  // 2

        vx_c = vx_n; vB_c = vB_n; vC_c = vC_n; z_c = z_n; dtr_c = dtr_n;
    }
}

extern "C" void kernel_launch(void* const* d_in, const int* in_sizes, int n_in,
                              void* d_out, int out_size, void* d_ws, size_t ws_size,
                              hipStream_t stream) {
    const float* u       = (const float*)d_in[0];
    const float* W_in    = (const float*)d_in[1];
    const float* conv_w  = (const float*)d_in[2];
    const float* conv_b  = (const float*)d_in[3];
    const float* R_x     = (const float*)d_in[4];
    const float* R_B     = (const float*)d_in[5];
    const float* R_C     = (const float*)d_in[6];
    const float* R_dt    = (const float*)d_in[7];
    const float* dt_bias = (const float*)d_in[8];
    const float* A_log   = (const float*)d_in[9];
    const float* Dv      = (const float*)d_in[10];
    const float* W_out   = (const float*)d_in[11];
    float* out = (float*)d_out;

    float* zx = (float*)d_ws;                      // [4096, 6168]
    float* yz = zx + (size_t)MROWS * DIP;          // [4096, 1536]

    {   // in-projection
        const int M = MROWS, N = DIP, K = DMODEL;
        const int grid = (M / 128) * ((N + 127) / 128);
        gemm_nt_f32<<<grid, 256, 0, stream>>>(u, W_in, zx, M, N, K);
    }
    mamba_scan5<<<B_SZ * NHEADS, 256, 0, stream>>>(
        zx, conv_w, conv_b, R_x, R_B, R_C, R_dt, dt_bias, A_log, Dv, yz);
    {   // out-projection
        const int M = MROWS, N = DMODEL, K = DINNER;
        const int grid = (M / 128) * ((N + 127) / 128);
        gemm_nt_f32<<<grid, 256, 0, stream>>>(yz, W_out, out, M, N, K);
    }
}

// Round 7
// 2326.440 us; speedup vs baseline: 2.0651x; 1.1044x over previous
//
#include <hip/hip_runtime.h>

#define B_SZ    2
#define LSEQ    2048
#define DMODEL  768
#define DINNER  1536
#define NHEADS  24
#define HD      64
#define CDPH    192
#define CONVDIM 4608
#define DIP     6168
#define MROWS   (B_SZ*LSEQ)   // 4096

typedef float f2 __attribute__((ext_vector_type(2)));
typedef float f32x4 __attribute__((ext_vector_type(4)));
typedef short bf16x8 __attribute__((ext_vector_type(8)));

__device__ __forceinline__ float siluf(float x) {
    return x / (1.0f + __expf(-x));
}

// lgkm-only barrier: global prefetches stay in flight across it.
#define WBAR() do { asm volatile("s_waitcnt lgkmcnt(0)" ::: "memory"); \
                    __builtin_amdgcn_s_barrier();                      \
                    asm volatile("" ::: "memory"); } while (0)

// Sum over the 4 g-groups (lane, lane^16, lane^32, lane^48), all lanes get it.
__device__ __forceinline__ float redux4(float v) {
    float o = __int_as_float(
        __builtin_amdgcn_ds_swizzle(__float_as_int(v), 0x401F));  // xor 16
    float s = v + o;
    float a = s, b = s;
    asm("v_permlane32_swap_b32 %0, %1" : "+v"(a), "+v"(b));
    return a + b;
}

__device__ __forceinline__ ushort f2bf(float v) {  // RNE f32 -> bf16 bits
    uint u = __float_as_uint(v);
    return (ushort)((u + 0x7FFFu + ((u >> 16) & 1u)) >> 16);
}
__device__ __forceinline__ float bf2f(ushort h) {
    return __uint_as_float(((uint)h) << 16);
}

// C[m,n] = sum_k A[m,k]*B[n,k], fp32 in/out, internally split-bf16 MFMA:
// a = hi+lo (bf16 each); acc += hi*hi + hi*lo + lo*hi  (lo*lo ~2^-16, dropped)
// 128x128 tile, BK=32, 256 thr = 4 waves (2x2 wave grid, 64x64 each).
__global__ __launch_bounds__(256) void gemm_nt_split(
    const float* __restrict__ A, const float* __restrict__ B,
    float* __restrict__ C, int M, int N, int K)
{
    __shared__ ushort As_hi[128][56];
    __shared__ ushort As_lo[128][56];
    __shared__ ushort Bs_hi[128][56];
    __shared__ ushort Bs_lo[128][56];

    const int ntn = (N + 127) >> 7;
    const int bm = blockIdx.x / ntn;
    const int bn = blockIdx.x - bm * ntn;
    const int m0 = bm << 7, n0 = bn << 7;
    const int tid = threadIdx.x;
    const int wid = tid >> 6;
    const int l = tid & 63;
    const int wm = wid >> 1, wn = wid & 1;       // 2x2 wave grid
    const int lr = l & 15;                       // fragment row/col lane
    const int kq = l >> 4;                       // k-quarter 0..3

    const int srow = tid >> 1;                   // staging row 0..127
    const int scol = (tid & 1) << 4;             // staging col 0 or 16
    const float* Ap = A + (size_t)(m0 + srow) * K + scol;
    const bool bok = (n0 + srow) < N;
    const float* Bp = B + (size_t)(n0 + srow) * K + scol;

    f32x4 acc[4][4];
#pragma unroll
    for (int i = 0; i < 4; ++i)
#pragma unroll
        for (int j = 0; j < 4; ++j) acc[i][j] = f32x4{0.f, 0.f, 0.f, 0.f};

    for (int k0 = 0; k0 < K; k0 += 32) {
        float av[16], bv[16];
#pragma unroll
        for (int q = 0; q < 4; ++q) {
            const float4 t = *(const float4*)(Ap + k0 + q * 4);
            av[q*4+0] = t.x; av[q*4+1] = t.y; av[q*4+2] = t.z; av[q*4+3] = t.w;
        }
#pragma unroll
        for (int q = 0; q < 4; ++q) {
            float4 t = make_float4(0.f, 0.f, 0.f, 0.f);
            if (bok) t = *(const float4*)(Bp + k0 + q * 4);
            bv[q*4+0] = t.x; bv[q*4+1] = t.y; bv[q*4+2] = t.z; bv[q*4+3] = t.w;
        }
        __syncthreads();
#pragma unroll
        for (int q = 0; q < 16; ++q) {
            const ushort ah = f2bf(av[q]);
            As_hi[srow][scol + q] = ah;
            As_lo[srow][scol + q] = f2bf(av[q] - bf2f(ah));
            const ushort bh = f2bf(bv[q]);
            Bs_hi[srow][scol + q] = bh;
            Bs_lo[srow][scol + q] = f2bf(bv[q] - bf2f(bh));
        }
        __syncthreads();

        bf16x8 ah[4], al[4], bh[4], bl[4];
#pragma unroll
        for (int f = 0; f < 4; ++f) {
            const int ra = wm * 64 + f * 16 + lr;
            ah[f] = *(const bf16x8*)&As_hi[ra][kq * 8];
            al[f] = *(const bf16x8*)&As_lo[ra][kq * 8];
            const int rb = wn * 64 + f * 16 + lr;
            bh[f] = *(const bf16x8*)&Bs_hi[rb][kq * 8];
            bl[f] = *(const bf16x8*)&Bs_lo[rb][kq * 8];
        }
#pragma unroll
        for (int i = 0; i < 4; ++i)
#pragma unroll
            for (int j = 0; j < 4; ++j) {
                acc[i][j] = __builtin_amdgcn_mfma_f32_16x16x32_bf16(
                    ah[i], bh[j], acc[i][j], 0, 0, 0);
                acc[i][j] = __builtin_amdgcn_mfma_f32_16x16x32_bf16(
                    ah[i], bl[j], acc[i][j], 0, 0, 0);
                acc[i][j] = __builtin_amdgcn_mfma_f32_16x16x32_bf16(
                    al[i], bh[j], acc[i][j], 0, 0, 0);
            }
    }

    // C/D layout (guide m89): col = lane&15, row = (lane>>4)*4 + reg
#pragma unroll
    for (int i = 0; i < 4; ++i) {
#pragma unroll
        for (int j = 0; j < 4; ++j) {
            const int n = n0 + wn * 64 + j * 16 + lr;
            if (n < N) {
#pragma unroll
                for (int rg = 0; rg < 4; ++rg) {
                    const int m = m0 + wm * 64 + i * 16 + kq * 4 + rg;
                    C[(size_t)m * N + n] = acc[i][j][rg];
                }
            }
        }
    }
}

// Scan: 2 independent (b,h) chains per block (8 waves). Within a chain:
// 4 waves, 2 lgkm barriers/step, swizzle+permlane reduces.
// Lane (w, g=l>>4, r=l&15): owns row p=16*w+r and state cols [16g,16g+16).
__global__ __launch_bounds__(512, 1) void mamba_scan6(
    const float* __restrict__ zx,      // [4096, DIP]
    const float* __restrict__ conv_w,  // [4608, 4]
    const float* __restrict__ conv_b,  // [4608]
    const float* __restrict__ R_x,     // [24,64,64]
    const float* __restrict__ R_B,
    const float* __restrict__ R_C,
    const float* __restrict__ R_dt,    // [24,64]
    const float* __restrict__ dt_bias, // [24]
    const float* __restrict__ A_log,   // [24]
    const float* __restrict__ Dvec,    // [24,64]
    float* __restrict__ yz)            // [4096, 1536]
{
    const int tid = threadIdx.x;
    const int ch = tid >> 8;                 // chain 0/1
    const int bh = blockIdx.x * 2 + ch;
    const int b = bh / NHEADS;
    const int h = bh % NHEADS;
    const int w = (tid >> 6) & 3;
    const int l = tid & 63;
    const int g = l >> 4;
    const int r = l & 15;
    const int p = (w << 4) + r;              // owned output row 0..63

    __shared__ __attribute__((aligned(16))) float ybuf[2][64];
    __shared__ __attribute__((aligned(16))) float Bml[2][64];
    __shared__ __attribute__((aligned(16))) float Cml[2][64];

    // R row-segments (row p, K-slice [16g,16g+16)) in registers
    f2 Rx2[8], Rb2[8], Rc2[8], Rd2[8];
    {
        const size_t ro = ((size_t)h * 64 + p) * 64 + (g << 4);
#pragma unroll
        for (int q = 0; q < 4; ++q) {
            const float4 v = *(const float4*)(R_x + ro + q * 4);
            Rx2[q*2] = f2{v.x, v.y}; Rx2[q*2+1] = f2{v.z, v.w};
        }
#pragma unroll
        for (int q = 0; q < 4; ++q) {
            const float4 v = *(const float4*)(R_B + ro + q * 4);
            Rb2[q*2] = f2{v.x, v.y}; Rb2[q*2+1] = f2{v.z, v.w};
        }
#pragma unroll
        for (int q = 0; q < 4; ++q) {
            const float4 v = *(const float4*)(R_C + ro + q * 4);
            Rc2[q*2] = f2{v.x, v.y}; Rc2[q*2+1] = f2{v.z, v.w};
        }
#pragma unroll
        for (int q = 0; q < 4; ++q) {
            const float4 v = *(const float4*)(R_dt + h * 64 + (g << 4) + q * 4);
            Rd2[q*2] = f2{v.x, v.y}; Rd2[q*2+1] = f2{v.z, v.w};
        }
    }
    const float Aval = -__expf(A_log[h]);
    const float bias = dt_bias[h];
    const float Dp   = Dvec[h * 64 + p];

    // conv params for channels p, 64+p, 128+p (g-redundant)
    float wx0, wx1, wx2, wx3, wb0, wb1, wb2, wb3, wc0, wc1, wc2, wc3;
    float cbx, cbB, cbC;
    {
        const float* cw = conv_w + (size_t)h * CDPH * 4;
        const float4 vx = *(const float4*)(cw + (size_t)p * 4);
        const float4 vb = *(const float4*)(cw + (size_t)(64 + p) * 4);
        const float4 vc = *(const float4*)(cw + (size_t)(128 + p) * 4);
        wx0 = vx.x; wx1 = vx.y; wx2 = vx.z; wx3 = vx.w;
        wb0 = vb.x; wb1 = vb.y; wb2 = vb.z; wb3 = vb.w;
        wc0 = vc.x; wc1 = vc.y; wc2 = vc.z; wc3 = vc.w;
        cbx = conv_b[h * CDPH + p];
        cbB = conv_b[h * CDPH + 64 + p];
        cbC = conv_b[h * CDPH + 128 + p];
    }
    float hx0 = 0.f, hx1 = 0.f, hx2 = 0.f;
    float hB0 = 0.f, hB1 = 0.f, hB2 = 0.f;
    float hC0 = 0.f, hC1 = 0.f, hC2 = 0.f;

    const float* xbc = zx + (size_t)b * LSEQ * DIP + DINNER + h * CDPH;
    const float* zb  = zx + (size_t)b * LSEQ * DIP + h * HD;
    const float* dtp = zx + (size_t)b * LSEQ * DIP + DINNER + CONVDIM + h;
    float* yzb = yz + (size_t)b * LSEQ * DINNER + h * HD;

    f2 st2[8];
#pragma unroll
    for (int q = 0; q < 8; ++q) st2[q] = f2{0.f, 0.f};

    if (g == 0) ybuf[ch][p] = 0.f;
    __syncthreads();

    float vx_c = xbc[p], vB_c = xbc[64 + p], vC_c = xbc[128 + p];
    float z_c = zb[p];
    float dtr_c = dtp[0];

    for (int t = 0; t < LSEQ; ++t) {
        // ---- conv (register history) ----
        const float xcx = fmaf(wx3, vx_c, fmaf(wx2, hx2, fmaf(wx1, hx1, fmaf(wx0, hx0, cbx))));
        const float xcB = fmaf(wb3, vB_c, fmaf(wb2, hB2, fmaf(wb1, hB1, fmaf(wb0, hB0, cbB))));
        const float xcC = fmaf(wc3, vC_c, fmaf(wc2, hC2, fmaf(wc1, hC1, fmaf(wc0, hC0, cbC))));
        hx0 = hx1; hx1 = hx2; hx2 = vx_c;
        hB0 = hB1; hB1 = hB2; hB2 = vB_c;
        hC0 = hC1; hC1 = hC2; hC2 = vC_c;

        // ---- prefetch t+1 (vmcnt-only; never drained by WBAR) ----
        const size_t roff = (size_t)((t + 1 < LSEQ) ? t + 1 : t) * DIP;
        const float vx_n = xbc[roff + p];
        const float vB_n = xbc[roff + 64 + p];
        const float vC_n = xbc[roff + 128 + p];
        const float z_n  = zb[roff + p];
        const float dtr_n = dtp[roff];

        // ---- phase A: 16-K partial dots for row p ----
        const float4* yb4 = (const float4*)(&ybuf[ch][g << 4]);
        f2 ax2 = {0.f, 0.f}, ab2 = {0.f, 0.f}, ac2 = {0.f, 0.f}, ad2 = {0.f, 0.f};
#pragma unroll
        for (int qq = 0; qq < 4; ++qq) {
            const float4 y4 = yb4[qq];
            const f2 ylo = {y4.x, y4.y}, yhi = {y4.z, y4.w};
            ax2 += Rx2[qq*2] * ylo; ax2 += Rx2[qq*2+1] * yhi;
            ab2 += Rb2[qq*2] * ylo; ab2 += Rb2[qq*2+1] * yhi;
            ac2 += Rc2[qq*2] * ylo; ac2 += Rc2[qq*2+1] * yhi;
            ad2 += Rd2[qq*2] * ylo; ad2 += Rd2[qq*2+1] * yhi;
        }
        const float ax = ax2.x + ax2.y, ab = ab2.x + ab2.y;
        const float ac = ac2.x + ac2.y, ad = ad2.x + ad2.y;

        // ---- reduce B,C; publish ----
        const float Bm = siluf(xcB + redux4(ab));
        const float Cm = siluf(xcC + redux4(ac));
        if (g == 0) { Bml[ch][p] = Bm; Cml[ch][p] = Cm; }
        WBAR();  // 1

        // ---- issue B/C window reads; overlap x/dt reduce + dt chain ----
        const float4* bm4 = (const float4*)(&Bml[ch][g << 4]);
        const float4* cm4 = (const float4*)(&Cml[ch][g << 4]);
        const float4 bA = bm4[0], bB = bm4[1], bC = bm4[2], bD = bm4[3];
        const float4 cA = cm4[0], cB = cm4[1], cC = cm4[2], cD = cm4[3];

        const float xv = siluf(xcx + redux4(ax));
        const float dv = dtr_c + redux4(ad) + bias;
        const float dtv = (dv > 15.f) ? dv : __logf(1.f + __expf(dv));
        const float dAv = __expf(dtv * Aval);
        const float kx = dtv * xv;
        const float zg = siluf(z_c);

        // ---- phase B: state update + y partial over cols [16g,16g+16) ----
        const f2 dA2 = {dAv, dAv};
        const f2 kx2 = {kx, kx};
        f2 bmv[8], cmv[8];
        bmv[0] = f2{bA.x, bA.y}; bmv[1] = f2{bA.z, bA.w};
        bmv[2] = f2{bB.x, bB.y}; bmv[3] = f2{bB.z, bB.w};
        bmv[4] = f2{bC.x, bC.y}; bmv[5] = f2{bC.z, bC.w};
        bmv[6] = f2{bD.x, bD.y}; bmv[7] = f2{bD.z, bD.w};
        cmv[0] = f2{cA.x, cA.y}; cmv[1] = f2{cA.z, cA.w};
        cmv[2] = f2{cB.x, cB.y}; cmv[3] = f2{cB.z, cB.w};
        cmv[4] = f2{cC.x, cC.y}; cmv[5] = f2{cC.z, cC.w};
        cmv[6] = f2{cD.x, cD.y}; cmv[7] = f2{cD.z, cD.w};
        f2 yp2 = {0.f, 0.f};
#pragma unroll
        for (int q = 0; q < 8; ++q) {
            st2[q] = st2[q] * dA2 + kx2 * bmv[q];
            yp2 += st2[q] * cmv[q];
        }
        float yp = yp2.x + yp2.y;
        yp = redux4(yp);
        const float ynew = yp + Dp * xv;

        if (g == 0) {
            ybuf[ch][p] = ynew;                          // next step's y_prev
            yzb[(size_t)t * DINNER + p] = ynew * zg;     // gated output
        }
        WBAR();  // 2

        vx_c = vx_n; vB_c = vB_n; vC_c = vC_n; z_c = z_n; dtr_c = dtr_n;
    }
}

extern "C" void kernel_launch(void* const* d_in, const int* in_sizes, int n_in,
                              void* d_out, int out_size, void* d_ws, size_t ws_size,
                              hipStream_t stream) {
    const float* u       = (const float*)d_in[0];
    const float* W_in    = (const float*)d_in[1];
    const float* conv_w  = (const float*)d_in[2];
    const float* conv_b  = (const float*)d_in[3];
    const float* R_x     = (const float*)d_in[4];
    const float* R_B     = (const float*)d_in[5];
    const float* R_C     = (const float*)d_in[6];
    const float* R_dt    = (const float*)d_in[7];
    const float* dt_bias = (const float*)d_in[8];
    const float* A_log   = (const float*)d_in[9];
    const float* Dv      = (const float*)d_in[10];
    const float* W_out   = (const float*)d_in[11];
    float* out = (float*)d_out;

    float* zx = (float*)d_ws;                      // [4096, 6168]
    float* yz = zx + (size_t)MROWS * DIP;          // [4096, 1536]

    {   // in-projection: 4096 x 6168 x 768, split-bf16 MFMA
        const int M = MROWS, N = DIP, K = DMODEL;
        const int grid = (M / 128) * ((N + 127) / 128);
        gemm_nt_split<<<grid, 256, 0, stream>>>(u, W_in, zx, M, N, K);
    }
    mamba_scan6<<<(B_SZ * NHEADS) / 2, 512, 0, stream>>>(
        zx, conv_w, conv_b, R_x, R_B, R_C, R_dt, dt_bias, A_log, Dv, yz);
    {   // out-projection: 4096 x 768 x 1536, split-bf16 MFMA
        const int M = MROWS, N = DMODEL, K = DINNER;
        const int grid = (M / 128) * ((N + 127) / 128);
        gemm_nt_split<<<grid, 256, 0, stream>>>(yz, W_out, out, M, N, K);
    }
}

// Round 8
// 2002.353 us; speedup vs baseline: 2.3994x; 1.1619x over previous
//
#include <hip/hip_runtime.h>

#define B_SZ    2
#define LSEQ    2048
#define DMODEL  768
#define DINNER  1536
#define NHEADS  24
#define HD      64
#define CDPH    192
#define CONVDIM 4608
#define DIP     6168
#define MROWS   (B_SZ*LSEQ)   // 4096

typedef float f2 __attribute__((ext_vector_type(2)));
typedef float f32x4 __attribute__((ext_vector_type(4)));
typedef short bf16x8 __attribute__((ext_vector_type(8)));

__device__ __forceinline__ float siluf(float x) {
    return x / (1.0f + __expf(-x));
}

// lgkm-only barrier: global prefetches stay in flight across it.
#define WBAR() do { asm volatile("s_waitcnt lgkmcnt(0)" ::: "memory"); \
                    __builtin_amdgcn_s_barrier();                      \
                    asm volatile("" ::: "memory"); } while (0)

// Sum over the 4 g-groups (lane, lane^16, lane^32, lane^48), all lanes get
// the result. Pure VALU: gfx950 v_permlane16_swap (xor-16 exchange) +
// v_permlane32_swap (xor-32 exchange). Zero LDS round-trips.
__device__ __forceinline__ float redux4(float v) {
    float a = v, b = v;
    asm("v_permlane16_swap_b32 %0, %1" : "+v"(a), "+v"(b));
    const float s = a + b;
    float c = s, d = s;
    asm("v_permlane32_swap_b32 %0, %1" : "+v"(c), "+v"(d));
    return c + d;
}

__device__ __forceinline__ ushort f2bf(float v) {  // RNE f32 -> bf16 bits
    uint u = __float_as_uint(v);
    return (ushort)((u + 0x7FFFu + ((u >> 16) & 1u)) >> 16);
}
__device__ __forceinline__ float bf2f(ushort h) {
    return __uint_as_float(((uint)h) << 16);
}

// C[m,n] = sum_k A[m,k]*B[n,k], fp32 in/out, internally split-bf16 MFMA:
// a = hi+lo (bf16 each); acc += hi*hi + hi*lo + lo*hi  (lo*lo ~2^-16, dropped)
// 128x128 tile, BK=32, 256 thr = 4 waves (2x2 wave grid, 64x64 each).
__global__ __launch_bounds__(256) void gemm_nt_split(
    const float* __restrict__ A, const float* __restrict__ B,
    float* __restrict__ C, int M, int N, int K)
{
    __shared__ ushort As_hi[128][56];
    __shared__ ushort As_lo[128][56];
    __shared__ ushort Bs_hi[128][56];
    __shared__ ushort Bs_lo[128][56];

    const int ntn = (N + 127) >> 7;
    const int bm = blockIdx.x / ntn;
    const int bn = blockIdx.x - bm * ntn;
    const int m0 = bm << 7, n0 = bn << 7;
    const int tid = threadIdx.x;
    const int wid = tid >> 6;
    const int l = tid & 63;
    const int wm = wid >> 1, wn = wid & 1;       // 2x2 wave grid
    const int lr = l & 15;                       // fragment row/col lane
    const int kq = l >> 4;                       // k-quarter 0..3

    const int srow = tid >> 1;                   // staging row 0..127
    const int scol = (tid & 1) << 4;             // staging col 0 or 16
    const float* Ap = A + (size_t)(m0 + srow) * K + scol;
    const bool bok = (n0 + srow) < N;
    const float* Bp = B + (size_t)(n0 + srow) * K + scol;

    f32x4 acc[4][4];
#pragma unroll
    for (int i = 0; i < 4; ++i)
#pragma unroll
        for (int j = 0; j < 4; ++j) acc[i][j] = f32x4{0.f, 0.f, 0.f, 0.f};

    for (int k0 = 0; k0 < K; k0 += 32) {
        float av[16], bv[16];
#pragma unroll
        for (int q = 0; q < 4; ++q) {
            const float4 t = *(const float4*)(Ap + k0 + q * 4);
            av[q*4+0] = t.x; av[q*4+1] = t.y; av[q*4+2] = t.z; av[q*4+3] = t.w;
        }
#pragma unroll
        for (int q = 0; q < 4; ++q) {
            float4 t = make_float4(0.f, 0.f, 0.f, 0.f);
            if (bok) t = *(const float4*)(Bp + k0 + q * 4);
            bv[q*4+0] = t.x; bv[q*4+1] = t.y; bv[q*4+2] = t.z; bv[q*4+3] = t.w;
        }
        __syncthreads();
#pragma unroll
        for (int q = 0; q < 16; ++q) {
            const ushort ah = f2bf(av[q]);
            As_hi[srow][scol + q] = ah;
            As_lo[srow][scol + q] = f2bf(av[q] - bf2f(ah));
            const ushort bh = f2bf(bv[q]);
            Bs_hi[srow][scol + q] = bh;
            Bs_lo[srow][scol + q] = f2bf(bv[q] - bf2f(bh));
        }
        __syncthreads();

        bf16x8 ah[4], al[4], bh[4], bl[4];
#pragma unroll
        for (int f = 0; f < 4; ++f) {
            const int ra = wm * 64 + f * 16 + lr;
            ah[f] = *(const bf16x8*)&As_hi[ra][kq * 8];
            al[f] = *(const bf16x8*)&As_lo[ra][kq * 8];
            const int rb = wn * 64 + f * 16 + lr;
            bh[f] = *(const bf16x8*)&Bs_hi[rb][kq * 8];
            bl[f] = *(const bf16x8*)&Bs_lo[rb][kq * 8];
        }
#pragma unroll
        for (int i = 0; i < 4; ++i)
#pragma unroll
            for (int j = 0; j < 4; ++j) {
                acc[i][j] = __builtin_amdgcn_mfma_f32_16x16x32_bf16(
                    ah[i], bh[j], acc[i][j], 0, 0, 0);
                acc[i][j] = __builtin_amdgcn_mfma_f32_16x16x32_bf16(
                    ah[i], bl[j], acc[i][j], 0, 0, 0);
                acc[i][j] = __builtin_amdgcn_mfma_f32_16x16x32_bf16(
                    al[i], bh[j], acc[i][j], 0, 0, 0);
            }
    }

    // C/D layout (guide m89): col = lane&15, row = (lane>>4)*4 + reg
#pragma unroll
    for (int i = 0; i < 4; ++i) {
#pragma unroll
        for (int j = 0; j < 4; ++j) {
            const int n = n0 + wn * 64 + j * 16 + lr;
            if (n < N) {
#pragma unroll
                for (int rg = 0; rg < 4; ++rg) {
                    const int m = m0 + wm * 64 + i * 16 + kq * 4 + rg;
                    C[(size_t)m * N + n] = acc[i][j][rg];
                }
            }
        }
    }
}

// 4-wave scan, 1 chain per block, 2 lgkm barriers/step, pure-VALU permlane
// reduces. Lane (w, g=l>>4, r=l&15): owns row p=16*w+r and state cols
// [16g,16g+16).
__global__ __launch_bounds__(256, 1) void mamba_scan7(
    const float* __restrict__ zx,      // [4096, DIP]
    const float* __restrict__ conv_w,  // [4608, 4]
    const float* __restrict__ conv_b,  // [4608]
    const float* __restrict__ R_x,     // [24,64,64]
    const float* __restrict__ R_B,
    const float* __restrict__ R_C,
    const float* __restrict__ R_dt,    // [24,64]
    const float* __restrict__ dt_bias, // [24]
    const float* __restrict__ A_log,   // [24]
    const float* __restrict__ Dvec,    // [24,64]
    float* __restrict__ yz)            // [4096, 1536]
{
    const int b = blockIdx.x / NHEADS;
    const int h = blockIdx.x % NHEADS;
    const int tid = threadIdx.x;
    const int w = tid >> 6;
    const int l = tid & 63;
    const int g = l >> 4;
    const int r = l & 15;
    const int p = (w << 4) + r;   // owned output row 0..63

    __shared__ __attribute__((aligned(16))) float ybuf[64];
    __shared__ __attribute__((aligned(16))) float Bml[64];
    __shared__ __attribute__((aligned(16))) float Cml[64];

    // R row-segments (row p, K-slice [16g,16g+16)) in registers
    f2 Rx2[8], Rb2[8], Rc2[8], Rd2[8];
    {
        const size_t ro = ((size_t)h * 64 + p) * 64 + (g << 4);
#pragma unroll
        for (int q = 0; q < 4; ++q) {
            const float4 v = *(const float4*)(R_x + ro + q * 4);
            Rx2[q*2] = f2{v.x, v.y}; Rx2[q*2+1] = f2{v.z, v.w};
        }
#pragma unroll
        for (int q = 0; q < 4; ++q) {
            const float4 v = *(const float4*)(R_B + ro + q * 4);
            Rb2[q*2] = f2{v.x, v.y}; Rb2[q*2+1] = f2{v.z, v.w};
        }
#pragma unroll
        for (int q = 0; q < 4; ++q) {
            const float4 v = *(const float4*)(R_C + ro + q * 4);
            Rc2[q*2] = f2{v.x, v.y}; Rc2[q*2+1] = f2{v.z, v.w};
        }
#pragma unroll
        for (int q = 0; q < 4; ++q) {
            const float4 v = *(const float4*)(R_dt + h * 64 + (g << 4) + q * 4);
            Rd2[q*2] = f2{v.x, v.y}; Rd2[q*2+1] = f2{v.z, v.w};
        }
    }
    const float Aval = -__expf(A_log[h]);
    const float bias = dt_bias[h];
    const float Dp   = Dvec[h * 64 + p];

    // conv params for channels p, 64+p, 128+p (g-redundant)
    float wx0, wx1, wx2, wx3, wb0, wb1, wb2, wb3, wc0, wc1, wc2, wc3;
    float cbx, cbB, cbC;
    {
        const float* cw = conv_w + (size_t)h * CDPH * 4;
        const float4 vx = *(const float4*)(cw + (size_t)p * 4);
        const float4 vb = *(const float4*)(cw + (size_t)(64 + p) * 4);
        const float4 vc = *(const float4*)(cw + (size_t)(128 + p) * 4);
        wx0 = vx.x; wx1 = vx.y; wx2 = vx.z; wx3 = vx.w;
        wb0 = vb.x; wb1 = vb.y; wb2 = vb.z; wb3 = vb.w;
        wc0 = vc.x; wc1 = vc.y; wc2 = vc.z; wc3 = vc.w;
        cbx = conv_b[h * CDPH + p];
        cbB = conv_b[h * CDPH + 64 + p];
        cbC = conv_b[h * CDPH + 128 + p];
    }
    float hx0 = 0.f, hx1 = 0.f, hx2 = 0.f;
    float hB0 = 0.f, hB1 = 0.f, hB2 = 0.f;
    float hC0 = 0.f, hC1 = 0.f, hC2 = 0.f;

    const float* xbc = zx + (size_t)b * LSEQ * DIP + DINNER + h * CDPH;
    const float* zb  = zx + (size_t)b * LSEQ * DIP + h * HD;
    const float* dtp = zx + (size_t)b * LSEQ * DIP + DINNER + CONVDIM + h;
    float* yzb = yz + (size_t)b * LSEQ * DINNER + h * HD;

    f2 st2[8];
#pragma unroll
    for (int q = 0; q < 8; ++q) st2[q] = f2{0.f, 0.f};

    if (g == 0) ybuf[p] = 0.f;
    __syncthreads();

    float vx_c = xbc[p], vB_c = xbc[64 + p], vC_c = xbc[128 + p];
    float z_c = zb[p];
    float dtr_c = dtp[0];
    int off = DIP;   // element offset of step t+1

    for (int t = 0; t < LSEQ; ++t) {
        // ---- conv (register history) ----
        const float xcx = fmaf(wx3, vx_c, fmaf(wx2, hx2, fmaf(wx1, hx1, fmaf(wx0, hx0, cbx))));
        const float xcB = fmaf(wb3, vB_c, fmaf(wb2, hB2, fmaf(wb1, hB1, fmaf(wb0, hB0, cbB))));
        const float xcC = fmaf(wc3, vC_c, fmaf(wc2, hC2, fmaf(wc1, hC1, fmaf(wc0, hC0, cbC))));
        hx0 = hx1; hx1 = hx2; hx2 = vx_c;
        hB0 = hB1; hB1 = hB2; hB2 = vB_c;
        hC0 = hC1; hC1 = hC2; hC2 = vC_c;

        // ---- prefetch t+1 (vmcnt-only; never drained by WBAR) ----
        const float vx_n = xbc[off + p];
        const float vB_n = xbc[off + 64 + p];
        const float vC_n = xbc[off + 128 + p];
        const float z_n  = zb[off + p];
        const float dtr_n = dtp[off];
        const float zg = siluf(z_c);   // hoisted: only depends on z_c

        // ---- phase A: 16-K partial dots for row p ----
        const float4* yb4 = (const float4*)(ybuf + (g << 4));
        f2 ax2 = {0.f, 0.f}, ab2 = {0.f, 0.f}, ac2 = {0.f, 0.f}, ad2 = {0.f, 0.f};
#pragma unroll
        for (int qq = 0; qq < 4; ++qq) {
            const float4 y4 = yb4[qq];
            const f2 ylo = {y4.x, y4.y}, yhi = {y4.z, y4.w};
            ax2 += Rx2[qq*2] * ylo; ax2 += Rx2[qq*2+1] * yhi;
            ab2 += Rb2[qq*2] * ylo; ab2 += Rb2[qq*2+1] * yhi;
            ac2 += Rc2[qq*2] * ylo; ac2 += Rc2[qq*2+1] * yhi;
            ad2 += Rd2[qq*2] * ylo; ad2 += Rd2[qq*2+1] * yhi;
        }
        const float ax = ax2.x + ax2.y, ab = ab2.x + ab2.y;
        const float ac = ac2.x + ac2.y, ad = ad2.x + ad2.y;

        // ---- reduce B,C (pure VALU); publish ----
        const float Bm = siluf(xcB + redux4(ab));
        const float Cm = siluf(xcC + redux4(ac));
        if (g == 0) { Bml[p] = Bm; Cml[p] = Cm; }
        WBAR();  // 1

        // ---- issue B/C window reads; overlap x/dt reduce + dt chain ----
        const float4* bm4 = (const float4*)(Bml + (g << 4));
        const float4* cm4 = (const float4*)(Cml + (g << 4));
        const float4 bA = bm4[0], bB = bm4[1], bC = bm4[2], bD = bm4[3];
        const float4 cA = cm4[0], cB = cm4[1], cC = cm4[2], cD = cm4[3];

        const float xv = siluf(xcx + redux4(ax));
        const float dv = dtr_c + redux4(ad) + bias;
        const float dtv = (dv > 15.f) ? dv : __logf(1.f + __expf(dv));
        const float dAv = __expf(dtv * Aval);
        const float kx = dtv * xv;

        // ---- phase B: state update + y partial over cols [16g,16g+16) ----
        const f2 dA2 = {dAv, dAv};
        const f2 kx2 = {kx, kx};
        f2 bmv[8], cmv[8];
        bmv[0] = f2{bA.x, bA.y}; bmv[1] = f2{bA.z, bA.w};
        bmv[2] = f2{bB.x, bB.y}; bmv[3] = f2{bB.z, bB.w};
        bmv[4] = f2{bC.x, bC.y}; bmv[5] = f2{bC.z, bC.w};
        bmv[6] = f2{bD.x, bD.y}; bmv[7] = f2{bD.z, bD.w};
        cmv[0] = f2{cA.x, cA.y}; cmv[1] = f2{cA.z, cA.w};
        cmv[2] = f2{cB.x, cB.y}; cmv[3] = f2{cB.z, cB.w};
        cmv[4] = f2{cC.x, cC.y}; cmv[5] = f2{cC.z, cC.w};
        cmv[6] = f2{cD.x, cD.y}; cmv[7] = f2{cD.z, cD.w};
        f2 yp2 = {0.f, 0.f};
#pragma unroll
        for (int q = 0; q < 8; ++q) {
            st2[q] = st2[q] * dA2 + kx2 * bmv[q];
            yp2 += st2[q] * cmv[q];
        }
        const float ynew = redux4(yp2.x + yp2.y) + Dp * xv;

        if (g == 0) {
            ybuf[p] = ynew;                              // next step's y_prev
            yzb[p] = ynew * zg;                          // gated output
        }
        WBAR();  // 2

        vx_c = vx_n; vB_c = vB_n; vC_c = vC_n; z_c = z_n; dtr_c = dtr_n;
        off += DIP;
        yzb += DINNER;
    }
}

extern "C" void kernel_launch(void* const* d_in, const int* in_sizes, int n_in,
                              void* d_out, int out_size, void* d_ws, size_t ws_size,
                              hipStream_t stream) {
    const float* u       = (const float*)d_in[0];
    const float* W_in    = (const float*)d_in[1];
    const float* conv_w  = (const float*)d_in[2];
    const float* conv_b  = (const float*)d_in[3];
    const float* R_x     = (const float*)d_in[4];
    const float* R_B     = (const float*)d_in[5];
    const float* R_C     = (const float*)d_in[6];
    const float* R_dt    = (const float*)d_in[7];
    const float* dt_bias = (const float*)d_in[8];
    const float* A_log   = (const float*)d_in[9];
    const float* Dv      = (const float*)d_in[10];
    const float* W_out   = (const float*)d_in[11];
    float* out = (float*)d_out;

    float* zx = (float*)d_ws;                      // [4096, 6168]
    float* yz = zx + (size_t)MROWS * DIP;          // [4096, 1536]

    {   // in-projection: 4096 x 6168 x 768, split-bf16 MFMA
        const int M = MROWS, N = DIP, K = DMODEL;
        const int grid = (M / 128) * ((N + 127) / 128);
        gemm_nt_split<<<grid, 256, 0, stream>>>(u, W_in, zx, M, N, K);
    }
    mamba_scan7<<<B_SZ * NHEADS, 256, 0, stream>>>(
        zx, conv_w, conv_b, R_x, R_B, R_C, R_dt, dt_bias, A_log, Dv, yz);
    {   // out-projection: 4096 x 768 x 1536, split-bf16 MFMA
        const int M = MROWS, N = DMODEL, K = DINNER;
        const int grid = (M / 128) * ((N + 127) / 128);
        gemm_nt_split<<<grid, 256, 0, stream>>>(yz, W_out, out, M, N, K);
    }
}